// Round 1
// 1422.103 us; speedup vs baseline: 1.2131x; 1.2131x over previous
//
#include <hip/hip_runtime.h>
#include <math.h>

#define B 128
#define L 2048
#define H 512
#define D 512
#define NG 2048   // 4*H
#define T 10
#define S 16      // L-chunks per batch row for attention partials
#define GB 256    // gates blocks fused in front of attention blocks

// workspace layout (float offsets); ws_size = 2 GiB
#define OFF_S    ((size_t)0)        // c state (attention query), B*H
#define OFF_H    ((size_t)65536)    // hidden h, B*H
#define OFF_X    ((size_t)131072)   // current x, B*D
#define OFF_SS   ((size_t)196608)   // ||s||^2 per b, B
#define OFF_G    ((size_t)196736)   // gates, B*NG
#define OFF_PL   ((size_t)460928)   // partial l, B*S
#define OFF_PCTX ((size_t)462976)   // partial ctx, B*S*H
#define OFF_RN   ((size_t)1511552)  // 1/||h_l||, B*L
#define OFF_HB   ((size_t)1773696)  // bf16 copy of hid_states, B*L*H bf16

__device__ __forceinline__ float sigf(float x){ return 1.0f / (1.0f + __expf(-x)); }

__device__ __forceinline__ unsigned int b16r(float f){   // fp32 -> bf16 bits, RNE
    unsigned int u = __float_as_uint(f);
    return (u + 0x7FFFu + ((u >> 16) & 1u)) >> 16;
}
__device__ __forceinline__ unsigned int pack2(float lo, float hi){
    return b16r(lo) | (b16r(hi) << 16);
}

#define UNPK(u, f0, f1) { f0 = __uint_as_float((u) << 16); f1 = __uint_as_float((u) & 0xFFFF0000u); }

__device__ __forceinline__ float block_sum256(float v){
    for (int off = 32; off; off >>= 1) v += __shfl_xor(v, off, 64);
    __shared__ float r[4];
    int wave = threadIdx.x >> 6, lane = threadIdx.x & 63;
    if (lane == 0) r[wave] = v;
    __syncthreads();
    return r[0] + r[1] + r[2] + r[3];
}

// ---- init: s=s0, h=h0, x=batch, ss=||s0||^2 ----
__global__ void init_k(const float* __restrict__ s0, const float* __restrict__ h0,
                       const float* __restrict__ x0, float* __restrict__ ws){
    int b = blockIdx.x, t = threadIdx.x;
    float ssq = 0.f;
    for (int h = t; h < H; h += 256){
        float sv = s0[b*H + h];
        ws[OFF_S + b*H + h] = sv;
        ws[OFF_H + b*H + h] = h0[b*H + h];
        ssq += sv * sv;
    }
    for (int d = t; d < D; d += 256) ws[OFF_X + b*D + d] = x0[b*D + d];
    float tot = block_sum256(ssq);
    if (t == 0) ws[OFF_SS + b] = tot;
}

// ---- load s (pre-scaled by 1/||s||) into 32 regs, 16-lane layout ----
__device__ __forceinline__ void load_snorm(const float* __restrict__ ws, int b, int g, float* sf){
    const float* sb = ws + OFF_S + (size_t)b * H + g * 8;
    float rssb = rsqrtf(ws[OFF_SS + b]);
    #pragma unroll
    for (int cb = 0; cb < 4; cb++){
        float4 a = *(const float4*)(sb + cb*128);
        float4 c = *(const float4*)(sb + cb*128 + 4);
        sf[cb*8+0]=a.x*rssb; sf[cb*8+1]=a.y*rssb; sf[cb*8+2]=a.z*rssb; sf[cb*8+3]=a.w*rssb;
        sf[cb*8+4]=c.x*rssb; sf[cb*8+5]=c.y*rssb; sf[cb*8+6]=c.z*rssb; sf[cb*8+7]=c.w*rssb;
    }
}

// ---- shared epilogue: combine r-groups + waves, write chunk partials ----
__device__ __forceinline__ void attn_epilogue(float* ctx, float lsum, float* smem,
                                              float* __restrict__ ws, int b, int chunk,
                                              int wave, int g, int r){
    #pragma unroll
    for (int k = 0; k < 32; k++){
        ctx[k] += __shfl_xor(ctx[k], 16, 64);
        ctx[k] += __shfl_xor(ctx[k], 32, 64);
    }
    lsum += __shfl_xor(lsum, 16, 64);
    lsum += __shfl_xor(lsum, 32, 64);

    float (*lctx)[512] = (float(*)[512])smem;   // 4*512 floats
    float* ll = smem + 2048;                    // 4 floats
    if (r == 0){
        #pragma unroll
        for (int cb = 0; cb < 4; cb++){
            float4 a = { ctx[cb*8+0], ctx[cb*8+1], ctx[cb*8+2], ctx[cb*8+3] };
            float4 c = { ctx[cb*8+4], ctx[cb*8+5], ctx[cb*8+6], ctx[cb*8+7] };
            *(float4*)&lctx[wave][cb*128 + g*8]     = a;
            *(float4*)&lctx[wave][cb*128 + g*8 + 4] = c;
        }
        if (g == 0) ll[wave] = lsum;
    }
    __syncthreads();
    int t = threadIdx.x;
    float* pc = ws + OFF_PCTX + ((size_t)b * S + chunk) * H;
    pc[t]       = lctx[0][t]     + lctx[1][t]     + lctx[2][t]     + lctx[3][t];
    pc[t + 256] = lctx[0][t+256] + lctx[1][t+256] + lctx[2][t+256] + lctx[3][t+256];
    if (t == 0) ws[OFF_PL + b*S + chunk] = ll[0] + ll[1] + ll[2] + ll[3];
}

// ---- step-0 attention: reads fp32 hid, emits bf16 copy + rn as side effect ----
__device__ __forceinline__ void attn_first_body(const float* __restrict__ hid,
                                                float* __restrict__ ws, int bid, float* smem){
    int b = bid >> 4, chunk = bid & (S - 1);
    int wave = threadIdx.x >> 6, lane = threadIdx.x & 63;
    int g = lane & 15, r = lane >> 4;
    float sf[32];
    load_snorm(ws, b, g, sf);

    int l0w = chunk * 128 + wave * 32;
    const float* hsrc = hid + ((size_t)b * L + l0w) * H + g * 8;
    uint4* hbdst = (uint4*)(ws + OFF_HB) + ((size_t)b * L + l0w) * 64 + g;
    float* rnw = ws + OFF_RN + (size_t)b * L + l0w;

    float ctx[32];
    #pragma unroll
    for (int k = 0; k < 32; k++) ctx[k] = 0.f;
    float lsum = 0.f;

    for (int it = 0; it < 8; it++){
        int ro = it*4 + r;
        const float* src = hsrc + (size_t)ro * H;
        float f[32];
        #pragma unroll
        for (int cb = 0; cb < 4; cb++){
            float4 a = *(const float4*)(src + cb*128);
            float4 c = *(const float4*)(src + cb*128 + 4);
            f[cb*8+0]=a.x; f[cb*8+1]=a.y; f[cb*8+2]=a.z; f[cb*8+3]=a.w;
            f[cb*8+4]=c.x; f[cb*8+5]=c.y; f[cb*8+6]=c.z; f[cb*8+7]=c.w;
        }
        float sq = 0.f, dot = 0.f;
        #pragma unroll
        for (int k = 0; k < 32; k++){ sq += f[k]*f[k]; dot += f[k]*sf[k]; }
        sq  += __shfl_xor(sq, 1, 64);  sq  += __shfl_xor(sq, 2, 64);
        sq  += __shfl_xor(sq, 4, 64);  sq  += __shfl_xor(sq, 8, 64);
        dot += __shfl_xor(dot, 1, 64); dot += __shfl_xor(dot, 2, 64);
        dot += __shfl_xor(dot, 4, 64); dot += __shfl_xor(dot, 8, 64);
        float rnv = rsqrtf(sq);
        if (g == 0) rnw[ro] = rnv;
        uint4* drow = hbdst + (size_t)ro * 64;
        #pragma unroll
        for (int cb = 0; cb < 4; cb++){
            uint4 o;
            o.x = pack2(f[cb*8+0], f[cb*8+1]);
            o.y = pack2(f[cb*8+2], f[cb*8+3]);
            o.z = pack2(f[cb*8+4], f[cb*8+5]);
            o.w = pack2(f[cb*8+6], f[cb*8+7]);
            drow[cb*16] = o;
        }
        float p = __expf(dot * rnv);          // cosine score in [-1,1] -> no max needed
        lsum += p;
        #pragma unroll
        for (int k = 0; k < 32; k++) ctx[k] += p * f[k];
    }
    attn_epilogue(ctx, lsum, smem, ws, b, chunk, wave, g, r);
}

// ---- steady-state attention on bf16 copy ----
__device__ __forceinline__ void attn_steady_body(float* __restrict__ ws, int bid, float* smem){
    int b = bid >> 4, chunk = bid & (S - 1);
    int wave = threadIdx.x >> 6, lane = threadIdx.x & 63;
    int g = lane & 15, r = lane >> 4;
    float sf[32];
    load_snorm(ws, b, g, sf);

    int l0w = chunk * 128 + wave * 32;
    const uint4* hbu = (const uint4*)(ws + OFF_HB) + ((size_t)b * L + l0w) * 64 + g;
    const float* rnp = ws + OFF_RN + (size_t)b * L + l0w;

    float ctx[32];
    #pragma unroll
    for (int k = 0; k < 32; k++) ctx[k] = 0.f;
    float lsum = 0.f;

    for (int it = 0; it < 8; it++){
        int ro = it*4 + r;
        const uint4* hr = hbu + (size_t)ro * 64;
        uint4 u0 = hr[0];
        uint4 u1 = hr[16];
        uint4 u2 = hr[32];
        uint4 u3 = hr[48];
        float rnv = rnp[ro];
        float f[32];
        UNPK(u0.x, f[0], f[1])   UNPK(u0.y, f[2], f[3])
        UNPK(u0.z, f[4], f[5])   UNPK(u0.w, f[6], f[7])
        UNPK(u1.x, f[8], f[9])   UNPK(u1.y, f[10], f[11])
        UNPK(u1.z, f[12], f[13]) UNPK(u1.w, f[14], f[15])
        UNPK(u2.x, f[16], f[17]) UNPK(u2.y, f[18], f[19])
        UNPK(u2.z, f[20], f[21]) UNPK(u2.w, f[22], f[23])
        UNPK(u3.x, f[24], f[25]) UNPK(u3.y, f[26], f[27])
        UNPK(u3.z, f[28], f[29]) UNPK(u3.w, f[30], f[31])
        float dot = 0.f;
        #pragma unroll
        for (int k = 0; k < 32; k++) dot += f[k] * sf[k];
        dot += __shfl_xor(dot, 1, 64);
        dot += __shfl_xor(dot, 2, 64);
        dot += __shfl_xor(dot, 4, 64);
        dot += __shfl_xor(dot, 8, 64);
        float p = __expf(dot * rnv);
        lsum += p;
        #pragma unroll
        for (int k = 0; k < 32; k++) ctx[k] += p * f[k];
    }
    attn_epilogue(ctx, lsum, smem, ws, b, chunk, wave, g, r);
}

// ---- gates = x @ W_ih + h @ W_hh + b ; outer-product, each weight read ONCE per block ----
// block: 256 thr = 32 n-threads (x4 cols = 128 cols) x 8 k-groups (64 k each); 8 batches/block
__device__ __forceinline__ void gates_body(const float* __restrict__ Wih,
                                           const float* __restrict__ Whh,
                                           const float* __restrict__ bias,
                                           float* __restrict__ ws,
                                           float* smem, int gid){
    int tid = threadIdx.x;
    int b0 = (gid >> 4) * 8, n0 = (gid & 15) * 128;
    float* xs  = smem;          // [8][512]
    float* hsm = smem + 4096;   // [8][512]
    {
        int r = tid >> 5, c = (tid & 31) * 16;
        const float* xsrc = ws + OFF_X + (size_t)(b0 + r) * D + c;
        const float* hsrc = ws + OFF_H + (size_t)(b0 + r) * H + c;
        #pragma unroll
        for (int j = 0; j < 4; j++){
            *(float4*)&xs[r*512 + c + j*4]  = *(const float4*)(xsrc + j*4);
            *(float4*)&hsm[r*512 + c + j*4] = *(const float4*)(hsrc + j*4);
        }
    }
    __syncthreads();
    int nt = tid & 31, kh = tid >> 5;
    int n = n0 + nt * 4;
    float4 acc[8];
    #pragma unroll
    for (int bi = 0; bi < 8; bi++){ acc[bi].x = 0.f; acc[bi].y = 0.f; acc[bi].z = 0.f; acc[bi].w = 0.f; }
    const float* w1p = Wih + (size_t)(kh * 64) * NG + n;
    const float* w2p = Whh + (size_t)(kh * 64) * NG + n;
    const float* xk = xs  + kh * 64;
    const float* hk = hsm + kh * 64;
    #pragma unroll 2
    for (int k = 0; k < 64; k++){
        float4 w1 = *(const float4*)(w1p + (size_t)k * NG);
        float4 w2 = *(const float4*)(w2p + (size_t)k * NG);
        #pragma unroll
        for (int bi = 0; bi < 8; bi++){
            float xv = xk[bi*512 + k], hv = hk[bi*512 + k];
            acc[bi].x += xv*w1.x + hv*w2.x;
            acc[bi].y += xv*w1.y + hv*w2.y;
            acc[bi].z += xv*w1.z + hv*w2.z;
            acc[bi].w += xv*w1.w + hv*w2.w;
        }
    }
    __syncthreads();                         // all LDS reads done before realias
    float4* red = (float4*)smem;             // [8 kh][8 bi][32 nt] = 8192 floats
    #pragma unroll
    for (int bi = 0; bi < 8; bi++) red[(kh*8 + bi)*32 + nt] = acc[bi];
    __syncthreads();
    int bi2 = tid >> 5, nt2 = tid & 31;
    int n2 = n0 + nt2 * 4;
    float4 s = *(const float4*)(bias + n2);
    #pragma unroll
    for (int k2 = 0; k2 < 8; k2++){
        float4 p = red[(k2*8 + bi2)*32 + nt2];
        s.x += p.x; s.y += p.y; s.z += p.z; s.w += p.w;
    }
    *(float4*)(ws + OFF_G + (size_t)(b0 + bi2)*NG + n2) = s;
}

// ---- fused launches: gates blocks first (overlap under attention BW phase) ----
__global__ __launch_bounds__(256) void fused0_k(const float* __restrict__ hid,
                                                const float* __restrict__ Wih,
                                                const float* __restrict__ Whh,
                                                const float* __restrict__ bias,
                                                float* __restrict__ ws){
    __shared__ float smem[8192];
    if (blockIdx.x < GB){ gates_body(Wih, Whh, bias, ws, smem, blockIdx.x); return; }
    attn_first_body(hid, ws, blockIdx.x - GB, smem);
}

__global__ __launch_bounds__(256) void fusedN_k(const float* __restrict__ Wih,
                                                const float* __restrict__ Whh,
                                                const float* __restrict__ bias,
                                                float* __restrict__ ws){
    __shared__ float smem[8192];
    if (blockIdx.x < GB){ gates_body(Wih, Whh, bias, ws, smem, blockIdx.x); return; }
    attn_steady_body(ws, blockIdx.x - GB, smem);
}

// ---- fused tail: combine + LSTM cell + MLP head + scatter; 512 threads ----
__global__ __launch_bounds__(512) void tail_k(const float* __restrict__ W1, const float* __restrict__ b1,
                                              const float* __restrict__ W2, const float* __restrict__ b2,
                                              float* __restrict__ ws, float* __restrict__ out, int st){
    int b = blockIdx.x, t = threadIdx.x;
    __shared__ float hl[512];
    __shared__ float part[8][64];
    __shared__ float t1[64];
    __shared__ float rr[8];

    float Ls = 0.f;
    #pragma unroll
    for (int i = 0; i < S; i++) Ls += ws[OFF_PL + b*S + i];
    float inv = 1.0f / Ls;

    float cx = 0.f;
    #pragma unroll
    for (int i = 0; i < S; i++) cx += ws[OFF_PCTX + ((size_t)b*S + i)*H + t];
    const float* g = ws + OFF_G + (size_t)b * NG;
    float sn = ws[OFF_S + b*H + t] + cx * inv;
    float gi = g[t], gf = g[512 + t], gg = g[1024 + t], go = g[1536 + t];
    float c  = sigf(gf) * sn + sigf(gi) * tanhf(gg);
    float hv = sigf(go) * tanhf(c);
    ws[OFF_S + b*H + t] = c;
    ws[OFF_H + b*H + t] = hv;
    hl[t] = hv;
    float csq = c * c;
    for (int off = 32; off; off >>= 1) csq += __shfl_xor(csq, off, 64);
    int wv = t >> 6, ln = t & 63;
    if (ln == 0) rr[wv] = csq;
    __syncthreads();
    if (t == 0){
        float s = 0.f;
        #pragma unroll
        for (int i = 0; i < 8; i++) s += rr[i];
        ws[OFF_SS + b] = s;
    }

    // MLP layer 1: 8-way k-split x 64 outputs
    int j = t & 63, q = t >> 6;
    float a = 0.f;
    #pragma unroll 4
    for (int k = q*64; k < q*64 + 64; k++) a += hl[k] * W1[k*64 + j];
    part[q][j] = a;
    __syncthreads();
    if (t < 64){
        float v = b1[t];
        #pragma unroll
        for (int i = 0; i < 8; i++) v += part[i][t];
        t1[t] = v > 0.f ? v : 0.01f * v;
    }
    __syncthreads();
    // MLP layer 2: one output per thread
    float a2 = b2[t];
    #pragma unroll
    for (int k = 0; k < 64; k++) a2 += t1[k] * W2[k*512 + t];
    ws[OFF_X + (size_t)b*D + t] = a2;
    int idx = st * D + t;
    out[(size_t)b * (D*T) + (size_t)(idx % T) * D + (idx / T)] = a2;
}

extern "C" void kernel_launch(void* const* d_in, const int* in_sizes, int n_in,
                              void* d_out, int out_size, void* d_ws, size_t ws_size,
                              hipStream_t stream) {
    const float* batch = (const float*)d_in[0];
    const float* hid   = (const float*)d_in[1];
    const float* h0    = (const float*)d_in[2];
    const float* s0    = (const float*)d_in[3];
    const float* Wih   = (const float*)d_in[4];
    const float* Whh   = (const float*)d_in[5];
    const float* bl    = (const float*)d_in[6];
    const float* W1    = (const float*)d_in[7];
    const float* b1    = (const float*)d_in[8];
    const float* W2    = (const float*)d_in[9];
    const float* b2    = (const float*)d_in[10];
    float* out = (float*)d_out;
    float* ws  = (float*)d_ws;

    init_k<<<B, 256, 0, stream>>>(s0, h0, batch, ws);
    fused0_k<<<B*S + GB, 256, 0, stream>>>(hid, Wih, Whh, bl, ws);
    tail_k<<<B, 512, 0, stream>>>(W1, b1, W2, b2, ws, out, 0);
    for (int st = 1; st < T; st++){
        fusedN_k<<<B*S + GB, 256, 0, stream>>>(Wih, Whh, bl, ws);
        tail_k<<<B, 512, 0, stream>>>(W1, b1, W2, b2, ws, out, st);
    }
}

// Round 2
// 1419.052 us; speedup vs baseline: 1.2157x; 1.0022x over previous
//
#include <hip/hip_runtime.h>
#include <math.h>

#define B 128
#define L 2048
#define H 512
#define D 512
#define NG 2048   // 4*H
#define T 10
#define S 16      // L-chunks per batch row for attention partials
#define GB 256    // gates blocks fused in front of attention blocks

// workspace layout (float offsets); ws_size = 2 GiB
#define OFF_S    ((size_t)0)        // c state (attention query), B*H
#define OFF_H    ((size_t)65536)    // hidden h, B*H
#define OFF_X    ((size_t)131072)   // current x, B*D
#define OFF_SS   ((size_t)196608)   // ||s||^2 per b, B
#define OFF_G    ((size_t)196736)   // gates, B*NG
#define OFF_PL   ((size_t)460928)   // partial l, B*S
#define OFF_PCTX ((size_t)462976)   // partial ctx, B*S*H
#define OFF_RN   ((size_t)1511552)  // 1/||h_l||, B*L
#define OFF_HB   ((size_t)1773696)  // bf16 copy of hid_states, B*L*H bf16

__device__ __forceinline__ float sigf(float x){ return 1.0f / (1.0f + __expf(-x)); }

__device__ __forceinline__ unsigned int b16r(float f){   // fp32 -> bf16 bits, RNE
    unsigned int u = __float_as_uint(f);
    return (u + 0x7FFFu + ((u >> 16) & 1u)) >> 16;
}
__device__ __forceinline__ unsigned int pack2(float lo, float hi){
    return b16r(lo) | (b16r(hi) << 16);
}

#define UNPK(u, f0, f1) { f0 = __uint_as_float((u) << 16); f1 = __uint_as_float((u) & 0xFFFF0000u); }

__device__ __forceinline__ float block_sum256(float v){
    for (int off = 32; off; off >>= 1) v += __shfl_xor(v, off, 64);
    __shared__ float r[4];
    int wave = threadIdx.x >> 6, lane = threadIdx.x & 63;
    if (lane == 0) r[wave] = v;
    __syncthreads();
    return r[0] + r[1] + r[2] + r[3];
}

// ---- init: s=s0, h=h0, x=batch, ss=||s0||^2 ----
__global__ void init_k(const float* __restrict__ s0, const float* __restrict__ h0,
                       const float* __restrict__ x0, float* __restrict__ ws){
    int b = blockIdx.x, t = threadIdx.x;
    float ssq = 0.f;
    for (int h = t; h < H; h += 256){
        float sv = s0[b*H + h];
        ws[OFF_S + b*H + h] = sv;
        ws[OFF_H + b*H + h] = h0[b*H + h];
        ssq += sv * sv;
    }
    for (int d = t; d < D; d += 256) ws[OFF_X + b*D + d] = x0[b*D + d];
    float tot = block_sum256(ssq);
    if (t == 0) ws[OFF_SS + b] = tot;
}

// ---- load s (pre-scaled by 1/||s||) into 32 regs, 16-lane layout ----
__device__ __forceinline__ void load_snorm(const float* __restrict__ ws, int b, int g, float* sf){
    const float* sb = ws + OFF_S + (size_t)b * H + g * 8;
    float rssb = rsqrtf(ws[OFF_SS + b]);
    #pragma unroll
    for (int cb = 0; cb < 4; cb++){
        float4 a = *(const float4*)(sb + cb*128);
        float4 c = *(const float4*)(sb + cb*128 + 4);
        sf[cb*8+0]=a.x*rssb; sf[cb*8+1]=a.y*rssb; sf[cb*8+2]=a.z*rssb; sf[cb*8+3]=a.w*rssb;
        sf[cb*8+4]=c.x*rssb; sf[cb*8+5]=c.y*rssb; sf[cb*8+6]=c.z*rssb; sf[cb*8+7]=c.w*rssb;
    }
}

// ---- shared epilogue: combine r-groups + waves, write chunk partials ----
__device__ __forceinline__ void attn_epilogue(float* ctx, float lsum, float* smem,
                                              float* __restrict__ ws, int b, int chunk,
                                              int wave, int g, int r){
    #pragma unroll
    for (int k = 0; k < 32; k++){
        ctx[k] += __shfl_xor(ctx[k], 16, 64);
        ctx[k] += __shfl_xor(ctx[k], 32, 64);
    }
    lsum += __shfl_xor(lsum, 16, 64);
    lsum += __shfl_xor(lsum, 32, 64);

    float (*lctx)[512] = (float(*)[512])smem;   // 4*512 floats
    float* ll = smem + 2048;                    // 4 floats
    if (r == 0){
        #pragma unroll
        for (int cb = 0; cb < 4; cb++){
            float4 a = { ctx[cb*8+0], ctx[cb*8+1], ctx[cb*8+2], ctx[cb*8+3] };
            float4 c = { ctx[cb*8+4], ctx[cb*8+5], ctx[cb*8+6], ctx[cb*8+7] };
            *(float4*)&lctx[wave][cb*128 + g*8]     = a;
            *(float4*)&lctx[wave][cb*128 + g*8 + 4] = c;
        }
        if (g == 0) ll[wave] = lsum;
    }
    __syncthreads();
    int t = threadIdx.x;
    float* pc = ws + OFF_PCTX + ((size_t)b * S + chunk) * H;
    pc[t]       = lctx[0][t]     + lctx[1][t]     + lctx[2][t]     + lctx[3][t];
    pc[t + 256] = lctx[0][t+256] + lctx[1][t+256] + lctx[2][t+256] + lctx[3][t+256];
    if (t == 0) ws[OFF_PL + b*S + chunk] = ll[0] + ll[1] + ll[2] + ll[3];
}

// ---- step-0 attention: reads fp32 hid, emits bf16 copy + rn as side effect ----
__device__ __forceinline__ void attn_first_body(const float* __restrict__ hid,
                                                float* __restrict__ ws, int bid, float* smem){
    int b = bid >> 4, chunk = bid & (S - 1);
    int wave = threadIdx.x >> 6, lane = threadIdx.x & 63;
    int g = lane & 15, r = lane >> 4;
    float sf[32];
    load_snorm(ws, b, g, sf);

    int l0w = chunk * 128 + wave * 32;
    const float* hsrc = hid + ((size_t)b * L + l0w) * H + g * 8;
    uint4* hbdst = (uint4*)(ws + OFF_HB) + ((size_t)b * L + l0w) * 64 + g;
    float* rnw = ws + OFF_RN + (size_t)b * L + l0w;

    float ctx[32];
    #pragma unroll
    for (int k = 0; k < 32; k++) ctx[k] = 0.f;
    float lsum = 0.f;

    for (int it = 0; it < 8; it++){
        int ro = it*4 + r;
        const float* src = hsrc + (size_t)ro * H;
        float f[32];
        #pragma unroll
        for (int cb = 0; cb < 4; cb++){
            float4 a = *(const float4*)(src + cb*128);
            float4 c = *(const float4*)(src + cb*128 + 4);
            f[cb*8+0]=a.x; f[cb*8+1]=a.y; f[cb*8+2]=a.z; f[cb*8+3]=a.w;
            f[cb*8+4]=c.x; f[cb*8+5]=c.y; f[cb*8+6]=c.z; f[cb*8+7]=c.w;
        }
        float sq = 0.f, dot = 0.f;
        #pragma unroll
        for (int k = 0; k < 32; k++){ sq += f[k]*f[k]; dot += f[k]*sf[k]; }
        sq  += __shfl_xor(sq, 1, 64);  sq  += __shfl_xor(sq, 2, 64);
        sq  += __shfl_xor(sq, 4, 64);  sq  += __shfl_xor(sq, 8, 64);
        dot += __shfl_xor(dot, 1, 64); dot += __shfl_xor(dot, 2, 64);
        dot += __shfl_xor(dot, 4, 64); dot += __shfl_xor(dot, 8, 64);
        float rnv = rsqrtf(sq);
        if (g == 0) rnw[ro] = rnv;
        uint4* drow = hbdst + (size_t)ro * 64;
        #pragma unroll
        for (int cb = 0; cb < 4; cb++){
            uint4 o;
            o.x = pack2(f[cb*8+0], f[cb*8+1]);
            o.y = pack2(f[cb*8+2], f[cb*8+3]);
            o.z = pack2(f[cb*8+4], f[cb*8+5]);
            o.w = pack2(f[cb*8+6], f[cb*8+7]);
            drow[cb*16] = o;
        }
        float p = __expf(dot * rnv);          // cosine score in [-1,1] -> no max needed
        lsum += p;
        #pragma unroll
        for (int k = 0; k < 32; k++) ctx[k] += p * f[k];
    }
    attn_epilogue(ctx, lsum, smem, ws, b, chunk, wave, g, r);
}

// ---- steady-state attention on bf16 copy ----
__device__ __forceinline__ void attn_steady_body(float* __restrict__ ws, int bid, float* smem){
    int b = bid >> 4, chunk = bid & (S - 1);
    int wave = threadIdx.x >> 6, lane = threadIdx.x & 63;
    int g = lane & 15, r = lane >> 4;
    float sf[32];
    load_snorm(ws, b, g, sf);

    int l0w = chunk * 128 + wave * 32;
    const uint4* hbu = (const uint4*)(ws + OFF_HB) + ((size_t)b * L + l0w) * 64 + g;
    const float* rnp = ws + OFF_RN + (size_t)b * L + l0w;

    float ctx[32];
    #pragma unroll
    for (int k = 0; k < 32; k++) ctx[k] = 0.f;
    float lsum = 0.f;

    for (int it = 0; it < 8; it++){
        int ro = it*4 + r;
        const uint4* hr = hbu + (size_t)ro * 64;
        uint4 u0 = hr[0];
        uint4 u1 = hr[16];
        uint4 u2 = hr[32];
        uint4 u3 = hr[48];
        float rnv = rnp[ro];
        float f[32];
        UNPK(u0.x, f[0], f[1])   UNPK(u0.y, f[2], f[3])
        UNPK(u0.z, f[4], f[5])   UNPK(u0.w, f[6], f[7])
        UNPK(u1.x, f[8], f[9])   UNPK(u1.y, f[10], f[11])
        UNPK(u1.z, f[12], f[13]) UNPK(u1.w, f[14], f[15])
        UNPK(u2.x, f[16], f[17]) UNPK(u2.y, f[18], f[19])
        UNPK(u2.z, f[20], f[21]) UNPK(u2.w, f[22], f[23])
        UNPK(u3.x, f[24], f[25]) UNPK(u3.y, f[26], f[27])
        UNPK(u3.z, f[28], f[29]) UNPK(u3.w, f[30], f[31])
        float dot = 0.f;
        #pragma unroll
        for (int k = 0; k < 32; k++) dot += f[k] * sf[k];
        dot += __shfl_xor(dot, 1, 64);
        dot += __shfl_xor(dot, 2, 64);
        dot += __shfl_xor(dot, 4, 64);
        dot += __shfl_xor(dot, 8, 64);
        float p = __expf(dot * rnv);
        lsum += p;
        #pragma unroll
        for (int k = 0; k < 32; k++) ctx[k] += p * f[k];
    }
    attn_epilogue(ctx, lsum, smem, ws, b, chunk, wave, g, r);
}

// ---- gates = x @ W_ih + h @ W_hh + b ; outer-product, each weight read ONCE per block ----
// block: 256 thr = 32 n-threads (x4 cols = 128 cols) x 8 k-groups (64 k each); 8 batches/block
__device__ __forceinline__ void gates_body(const float* __restrict__ Wih,
                                           const float* __restrict__ Whh,
                                           const float* __restrict__ bias,
                                           float* __restrict__ ws,
                                           float* smem, int gid){
    int tid = threadIdx.x;
    int b0 = (gid >> 4) * 8, n0 = (gid & 15) * 128;
    float* xs  = smem;          // [8][512]
    float* hsm = smem + 4096;   // [8][512]
    {
        int r = tid >> 5, c = (tid & 31) * 16;
        const float* xsrc = ws + OFF_X + (size_t)(b0 + r) * D + c;
        const float* hsrc = ws + OFF_H + (size_t)(b0 + r) * H + c;
        #pragma unroll
        for (int j = 0; j < 4; j++){
            *(float4*)&xs[r*512 + c + j*4]  = *(const float4*)(xsrc + j*4);
            *(float4*)&hsm[r*512 + c + j*4] = *(const float4*)(hsrc + j*4);
        }
    }
    __syncthreads();
    int nt = tid & 31, kh = tid >> 5;
    int n = n0 + nt * 4;
    float4 acc[8];
    #pragma unroll
    for (int bi = 0; bi < 8; bi++){ acc[bi].x = 0.f; acc[bi].y = 0.f; acc[bi].z = 0.f; acc[bi].w = 0.f; }
    const float* w1p = Wih + (size_t)(kh * 64) * NG + n;
    const float* w2p = Whh + (size_t)(kh * 64) * NG + n;
    const float* xk = xs  + kh * 64;
    const float* hk = hsm + kh * 64;
    #pragma unroll 2
    for (int k = 0; k < 64; k++){
        float4 w1 = *(const float4*)(w1p + (size_t)k * NG);
        float4 w2 = *(const float4*)(w2p + (size_t)k * NG);
        #pragma unroll
        for (int bi = 0; bi < 8; bi++){
            float xv = xk[bi*512 + k], hv = hk[bi*512 + k];
            acc[bi].x += xv*w1.x + hv*w2.x;
            acc[bi].y += xv*w1.y + hv*w2.y;
            acc[bi].z += xv*w1.z + hv*w2.z;
            acc[bi].w += xv*w1.w + hv*w2.w;
        }
    }
    __syncthreads();                         // all LDS reads done before realias
    float4* red = (float4*)smem;             // [8 kh][8 bi][32 nt] = 8192 floats
    #pragma unroll
    for (int bi = 0; bi < 8; bi++) red[(kh*8 + bi)*32 + nt] = acc[bi];
    __syncthreads();
    int bi2 = tid >> 5, nt2 = tid & 31;
    int n2 = n0 + nt2 * 4;
    float4 s = *(const float4*)(bias + n2);
    #pragma unroll
    for (int k2 = 0; k2 < 8; k2++){
        float4 p = red[(k2*8 + bi2)*32 + nt2];
        s.x += p.x; s.y += p.y; s.z += p.z; s.w += p.w;
    }
    *(float4*)(ws + OFF_G + (size_t)(b0 + bi2)*NG + n2) = s;
}

// ---- fused launches: gates blocks first (overlap under attention BW phase) ----
// __launch_bounds__(256, 3): min 3 waves/EU -> VGPR cap ~170. Without this the
// compiler targeted 8 waves/EU (60 VGPR) and spilled sf[32]+ctx[32]+f[32]
// (~130 live floats) to scratch: ~1.6 GB scratch traffic per attention pass.
__global__ __launch_bounds__(256, 3) void fused0_k(const float* __restrict__ hid,
                                                   const float* __restrict__ Wih,
                                                   const float* __restrict__ Whh,
                                                   const float* __restrict__ bias,
                                                   float* __restrict__ ws){
    __shared__ float smem[8192];
    if (blockIdx.x < GB){ gates_body(Wih, Whh, bias, ws, smem, blockIdx.x); return; }
    attn_first_body(hid, ws, blockIdx.x - GB, smem);
}

__global__ __launch_bounds__(256, 3) void fusedN_k(const float* __restrict__ Wih,
                                                   const float* __restrict__ Whh,
                                                   const float* __restrict__ bias,
                                                   float* __restrict__ ws){
    __shared__ float smem[8192];
    if (blockIdx.x < GB){ gates_body(Wih, Whh, bias, ws, smem, blockIdx.x); return; }
    attn_steady_body(ws, blockIdx.x - GB, smem);
}

// ---- fused tail: combine + LSTM cell + MLP head + scatter; 512 threads ----
__global__ __launch_bounds__(512) void tail_k(const float* __restrict__ W1, const float* __restrict__ b1,
                                              const float* __restrict__ W2, const float* __restrict__ b2,
                                              float* __restrict__ ws, float* __restrict__ out, int st){
    int b = blockIdx.x, t = threadIdx.x;
    __shared__ float hl[512];
    __shared__ float part[8][64];
    __shared__ float t1[64];
    __shared__ float rr[8];

    float Ls = 0.f;
    #pragma unroll
    for (int i = 0; i < S; i++) Ls += ws[OFF_PL + b*S + i];
    float inv = 1.0f / Ls;

    float cx = 0.f;
    #pragma unroll
    for (int i = 0; i < S; i++) cx += ws[OFF_PCTX + ((size_t)b*S + i)*H + t];
    const float* g = ws + OFF_G + (size_t)b * NG;
    float sn = ws[OFF_S + b*H + t] + cx * inv;
    float gi = g[t], gf = g[512 + t], gg = g[1024 + t], go = g[1536 + t];
    float c  = sigf(gf) * sn + sigf(gi) * tanhf(gg);
    float hv = sigf(go) * tanhf(c);
    ws[OFF_S + b*H + t] = c;
    ws[OFF_H + b*H + t] = hv;
    hl[t] = hv;
    float csq = c * c;
    for (int off = 32; off; off >>= 1) csq += __shfl_xor(csq, off, 64);
    int wv = t >> 6, ln = t & 63;
    if (ln == 0) rr[wv] = csq;
    __syncthreads();
    if (t == 0){
        float s = 0.f;
        #pragma unroll
        for (int i = 0; i < 8; i++) s += rr[i];
        ws[OFF_SS + b] = s;
    }

    // MLP layer 1: 8-way k-split x 64 outputs
    int j = t & 63, q = t >> 6;
    float a = 0.f;
    #pragma unroll 4
    for (int k = q*64; k < q*64 + 64; k++) a += hl[k] * W1[k*64 + j];
    part[q][j] = a;
    __syncthreads();
    if (t < 64){
        float v = b1[t];
        #pragma unroll
        for (int i = 0; i < 8; i++) v += part[i][t];
        t1[t] = v > 0.f ? v : 0.01f * v;
    }
    __syncthreads();
    // MLP layer 2: one output per thread
    float a2 = b2[t];
    #pragma unroll
    for (int k = 0; k < 64; k++) a2 += t1[k] * W2[k*512 + t];
    ws[OFF_X + (size_t)b*D + t] = a2;
    int idx = st * D + t;
    out[(size_t)b * (D*T) + (size_t)(idx % T) * D + (idx / T)] = a2;
}

extern "C" void kernel_launch(void* const* d_in, const int* in_sizes, int n_in,
                              void* d_out, int out_size, void* d_ws, size_t ws_size,
                              hipStream_t stream) {
    const float* batch = (const float*)d_in[0];
    const float* hid   = (const float*)d_in[1];
    const float* h0    = (const float*)d_in[2];
    const float* s0    = (const float*)d_in[3];
    const float* Wih   = (const float*)d_in[4];
    const float* Whh   = (const float*)d_in[5];
    const float* bl    = (const float*)d_in[6];
    const float* W1    = (const float*)d_in[7];
    const float* b1    = (const float*)d_in[8];
    const float* W2    = (const float*)d_in[9];
    const float* b2    = (const float*)d_in[10];
    float* out = (float*)d_out;
    float* ws  = (float*)d_ws;

    init_k<<<B, 256, 0, stream>>>(s0, h0, batch, ws);
    fused0_k<<<B*S + GB, 256, 0, stream>>>(hid, Wih, Whh, bl, ws);
    tail_k<<<B, 512, 0, stream>>>(W1, b1, W2, b2, ws, out, 0);
    for (int st = 1; st < T; st++){
        fusedN_k<<<B*S + GB, 256, 0, stream>>>(Wih, Whh, bl, ws);
        tail_k<<<B, 512, 0, stream>>>(W1, b1, W2, b2, ws, out, st);
    }
}